// Round 1
// baseline (40123.138 us; speedup 1.0000x reference)
//
#include <hip/hip_runtime.h>
#include <math.h>

#define T_DIM 1024
#define B_DIM 64
#define H_DIM 512
#define HID   512
#define EPS_F 1e-5f

// ---- ws layout (float offsets) ----
#define WS_SUM    0                       // 512
#define WS_SUMSQ  512                     // 512
#define WS_A      1024                    // 512  (scale * rstd)
#define WS_C0     1536                    // 512  (bias - mean*a)
#define WS_HBUF   4096                    // [2 parity][2 dir][64 b][512] = 131072
#define WS_CBUF   (4096 + 131072)         // [2 dir][64 b][512] = 65536
#define WS_XZ     (4096 + 131072 + 65536) // [2 parity][2 dir][64 b][2048] = 524288
#define WS_END    (WS_XZ + 524288)        // 724992 floats (~2.9 MB)

__device__ __forceinline__ float sigf(float v) {
    return 1.0f / (1.0f + __expf(-v));
}

// ---------------- BatchNorm column statistics ----------------
// grid (2, 128), block 256. col = bx*256+tid, 512 rows per by.
__global__ void stats_kernel(const float* __restrict__ x, float* __restrict__ ws) {
    int col = blockIdx.x * 256 + threadIdx.x;
    int row0 = blockIdx.y * 512;
    float s = 0.f, s2 = 0.f;
    for (int r = 0; r < 512; ++r) {
        float v = x[(size_t)(row0 + r) * H_DIM + col];
        s += v;
        s2 += v * v;
    }
    atomicAdd(&ws[WS_SUM + col], s);
    atomicAdd(&ws[WS_SUMSQ + col], s2);
}

// 1 block, 512 threads: fold BN into y = x*a + c0 (then *mask)
__global__ void finalize_kernel(const int* __restrict__ lengths,
                                const float* __restrict__ scale,
                                const float* __restrict__ bias,
                                const int* __restrict__ training,
                                float* __restrict__ ws) {
    __shared__ float cnt_sh;
    int tid = threadIdx.x;
    if (tid == 0) {
        int c = 0;
        for (int b = 0; b < B_DIM; ++b) c += lengths[b];
        cnt_sh = (float)c;
    }
    __syncthreads();
    float a, c0;
    if (*training) {
        float inv = 1.0f / cnt_sh;
        float mean = ws[WS_SUM + tid] * inv;
        float mean2 = ws[WS_SUMSQ + tid] * inv;
        float var = fmaxf(0.0f, mean2 - mean * mean);
        a = scale[tid] * rsqrtf(var + EPS_F);
        c0 = bias[tid] - mean * a;
    } else {
        a = scale[tid] * rsqrtf(1.0f + EPS_F);
        c0 = bias[tid];
    }
    ws[WS_A + tid] = a;
    ws[WS_C0 + tid] = c0;
}

// ---------------- per-timestep kernel ----------------
// grid 128 x 256 threads.
// role 0 (blocks 0..63):  z = xz[t] + h_{t-1} @ Wh -> gates -> h_t, c_t, += out
// role 1 (blocks 64..127): xz[t+1] = BN(x[t+1]) @ Wx + b   (independent of recurrence)
// t = -1: prime (role 1 computes xz[0], role 0 idles)
__launch_bounds__(256)
__global__ void step_kernel(int t,
                            const float* __restrict__ x,
                            const int* __restrict__ lengths,
                            const float* __restrict__ mask,
                            const float* __restrict__ Wx_f, const float* __restrict__ Wh_f,
                            const float* __restrict__ b_f,
                            const float* __restrict__ Wx_b, const float* __restrict__ Wh_b,
                            const float* __restrict__ b_b,
                            float* __restrict__ ws, float* __restrict__ out) {
    // A staged transposed [k][b] stride 68 (row = 272B, 16B-aligned; 2-way banks on reads)
    __shared__ __align__(16) float As[64 * 68];
    __shared__ __align__(16) float Ws_[64 * 68];

    const int role = blockIdx.x >> 6;
    const int r6   = blockIdx.x & 63;
    const int dir  = r6 >> 5;
    const int jt   = r6 & 31;
    const int tid  = threadIdx.x;
    const int tidb = tid & 15;   // b-quad: b0 = 4*tidb
    const int tidn = tid >> 4;   // n-quad: n0 = 4*tidn
    const int b0   = tidb << 2;
    const int n0   = tidn << 2;

    const int target = t + 1;                 // time row produced by role 1
    if (role == 0 && t < 0) return;           // block-uniform
    if (role == 1 && target >= T_DIM) return; // block-uniform

    const int g   = tidn >> 2;                // gate of this thread's 4 cols
    const int jj0 = (tidn & 3) << 2;
    const int col_base = g * 512 + jt * 16 + jj0;  // 4 contiguous weight cols

    const float* W  = (role == 1) ? (dir ? Wx_b : Wx_f) : (dir ? Wh_b : Wh_f);
    const float* bv = dir ? b_b : b_f;

    float acc[4][4];
    if (role == 0) {
        const int xzb = ((t & 1) * 2 + dir) * (B_DIM * 2048);
#pragma unroll
        for (int i = 0; i < 4; ++i) {
            float4 v = *reinterpret_cast<const float4*>(&ws[WS_XZ + xzb + (b0 + i) * 2048 + col_base]);
            acc[i][0] = v.x; acc[i][1] = v.y; acc[i][2] = v.z; acc[i][3] = v.w;
        }
    } else {
        float4 bvv = *reinterpret_cast<const float4*>(&bv[col_base]);
#pragma unroll
        for (int i = 0; i < 4; ++i) {
            acc[i][0] = bvv.x; acc[i][1] = bvv.y; acc[i][2] = bvv.z; acc[i][3] = bvv.w;
        }
    }

    const int hbase_in = ((t & 1) * 2 + dir) * (B_DIM * 512);

    for (int ck = 0; ck < 8; ++ck) {
        const int k0c = ck * 64;
        // ---- stage A chunk: [64 k][64 b], source is h_prev (role0) or BN(x) (role1)
#pragma unroll
        for (int i = 0; i < 4; ++i) {
            int f4  = tid + i * 256;       // 0..1023
            int kk4 = f4 & 15;
            int b   = f4 >> 4;
            int k   = k0c + (kk4 << 2);
            float4 v;
            if (role == 0) {
                v = *reinterpret_cast<const float4*>(&ws[WS_HBUF + hbase_in + b * 512 + k]);
            } else {
                int trow;
                if (dir == 0) {
                    trow = target;
                } else {
                    trow = lengths[b] - 1 - target;
                    if (trow < 0) trow += T_DIM;
                }
                float4 xv = *reinterpret_cast<const float4*>(&x[((size_t)trow * B_DIM + b) * H_DIM + k]);
                float  m  = mask[(size_t)trow * B_DIM + b];
                float4 av = *reinterpret_cast<const float4*>(&ws[WS_A + k]);
                float4 cv = *reinterpret_cast<const float4*>(&ws[WS_C0 + k]);
                v.x = (xv.x * av.x + cv.x) * m;
                v.y = (xv.y * av.y + cv.y) * m;
                v.z = (xv.z * av.z + cv.z) * m;
                v.w = (xv.w * av.w + cv.w) * m;
            }
            int kr = kk4 << 2;
            As[(kr + 0) * 68 + b] = v.x;
            As[(kr + 1) * 68 + b] = v.y;
            As[(kr + 2) * 68 + b] = v.z;
            As[(kr + 3) * 68 + b] = v.w;
        }
        // ---- stage W chunk: [64 k][64 n]
#pragma unroll
        for (int i = 0; i < 4; ++i) {
            int f4  = tid + i * 256;
            int n4  = f4 & 15;
            int kk  = f4 >> 4;
            int nl  = n4 << 2;
            int gg  = nl >> 4;
            int jj  = nl & 15;
            int colw = gg * 512 + jt * 16 + jj;
            float4 wv = *reinterpret_cast<const float4*>(&W[(size_t)(k0c + kk) * 2048 + colw]);
            *reinterpret_cast<float4*>(&Ws_[kk * 68 + nl]) = wv;
        }
        __syncthreads();
        // ---- inner: per k, 2x ds_read_b128 + 16 FMA
#pragma unroll 4
        for (int kk = 0; kk < 64; ++kk) {
            const float4 a4 = *reinterpret_cast<const float4*>(&As[kk * 68 + b0]);
            const float4 w4 = *reinterpret_cast<const float4*>(&Ws_[kk * 68 + n0]);
            acc[0][0] += a4.x * w4.x; acc[0][1] += a4.x * w4.y; acc[0][2] += a4.x * w4.z; acc[0][3] += a4.x * w4.w;
            acc[1][0] += a4.y * w4.x; acc[1][1] += a4.y * w4.y; acc[1][2] += a4.y * w4.z; acc[1][3] += a4.y * w4.w;
            acc[2][0] += a4.z * w4.x; acc[2][1] += a4.z * w4.y; acc[2][2] += a4.z * w4.z; acc[2][3] += a4.z * w4.w;
            acc[3][0] += a4.w * w4.x; acc[3][1] += a4.w * w4.y; acc[3][2] += a4.w * w4.z; acc[3][3] += a4.w * w4.w;
        }
        __syncthreads();
    }

    if (role == 1) {
        // store xz[target]
        const int xzb = ((target & 1) * 2 + dir) * (B_DIM * 2048);
#pragma unroll
        for (int i = 0; i < 4; ++i) {
            float4 v = make_float4(acc[i][0], acc[i][1], acc[i][2], acc[i][3]);
            *reinterpret_cast<float4*>(&ws[WS_XZ + xzb + (b0 + i) * 2048 + col_base]) = v;
        }
        return;
    }

    // ---- role 0: gate phase. Exchange z tile through LDS (reuse As as zs[64][68]).
    float* zs = As;
#pragma unroll
    for (int i = 0; i < 4; ++i) {
        float4 v = make_float4(acc[i][0], acc[i][1], acc[i][2], acc[i][3]);
        *reinterpret_cast<float4*>(&zs[(b0 + i) * 68 + n0]) = v;
    }
    __syncthreads();

    const int b   = tid >> 2;          // 0..63
    const int jjg = (tid & 3) << 2;    // 0,4,8,12
    const int hc  = jt * 16 + jjg;     // h-column base (4 cols)

    float4 zi = *reinterpret_cast<const float4*>(&zs[b * 68 +  0 + jjg]);
    float4 zf = *reinterpret_cast<const float4*>(&zs[b * 68 + 16 + jjg]);
    float4 zg = *reinterpret_cast<const float4*>(&zs[b * 68 + 32 + jjg]);
    float4 zo = *reinterpret_cast<const float4*>(&zs[b * 68 + 48 + jjg]);

    float* cptr = &ws[WS_CBUF + (dir * B_DIM + b) * 512 + hc];
    float4 c4 = *reinterpret_cast<const float4*>(cptr);

    float cn[4], hv[4];
    {
        float c = sigf(zf.x) * c4.x + sigf(zi.x) * tanhf(zg.x);
        cn[0] = c; hv[0] = sigf(zo.x) * tanhf(c);
    }
    {
        float c = sigf(zf.y) * c4.y + sigf(zi.y) * tanhf(zg.y);
        cn[1] = c; hv[1] = sigf(zo.y) * tanhf(c);
    }
    {
        float c = sigf(zf.z) * c4.z + sigf(zi.z) * tanhf(zg.z);
        cn[2] = c; hv[2] = sigf(zo.z) * tanhf(c);
    }
    {
        float c = sigf(zf.w) * c4.w + sigf(zi.w) * tanhf(zg.w);
        cn[3] = c; hv[3] = sigf(zo.w) * tanhf(c);
    }

    *reinterpret_cast<float4*>(cptr) = make_float4(cn[0], cn[1], cn[2], cn[3]);

    const int hbase_out = (((t + 1) & 1) * 2 + dir) * (B_DIM * 512);
    *reinterpret_cast<float4*>(&ws[WS_HBUF + hbase_out + b * 512 + hc]) =
        make_float4(hv[0], hv[1], hv[2], hv[3]);

    int orow;
    if (dir == 0) {
        orow = t;
    } else {
        orow = lengths[b] - 1 - t;
        if (orow < 0) orow += T_DIM;
    }
    float* op = &out[((size_t)orow * B_DIM + b) * HID + hc];
    atomicAdd(&op[0], hv[0]);
    atomicAdd(&op[1], hv[1]);
    atomicAdd(&op[2], hv[2]);
    atomicAdd(&op[3], hv[3]);
}

extern "C" void kernel_launch(void* const* d_in, const int* in_sizes, int n_in,
                              void* d_out, int out_size, void* d_ws, size_t ws_size,
                              hipStream_t stream) {
    const float* x        = (const float*)d_in[0];
    const int*   lengths  = (const int*)d_in[1];
    const float* mask     = (const float*)d_in[2];
    const float* scale    = (const float*)d_in[3];
    const float* bias     = (const float*)d_in[4];
    const float* Wx_f     = (const float*)d_in[5];
    const float* Wh_f     = (const float*)d_in[6];
    const float* b_f      = (const float*)d_in[7];
    const float* Wx_b     = (const float*)d_in[8];
    const float* Wh_b     = (const float*)d_in[9];
    const float* b_b      = (const float*)d_in[10];
    const int*   training = (const int*)d_in[11];
    float* ws  = (float*)d_ws;
    float* out = (float*)d_out;

    // zero stats + h/c state + xz buffers (~2.9 MB) and the accumulated output
    hipMemsetAsync(ws, 0, (size_t)WS_END * sizeof(float), stream);
    hipMemsetAsync(out, 0, (size_t)out_size * sizeof(float), stream);

    stats_kernel<<<dim3(2, 128), 256, 0, stream>>>(x, ws);
    finalize_kernel<<<1, 512, 0, stream>>>(lengths, scale, bias, training, ws);

    for (int t = -1; t < T_DIM; ++t) {
        step_kernel<<<128, 256, 0, stream>>>(t, x, lengths, mask,
                                             Wx_f, Wh_f, b_f, Wx_b, Wh_b, b_b,
                                             ws, out);
    }
}